// Round 24
// baseline (420.319 us; speedup 1.0000x reference)
//
#include <hip/hip_runtime.h>
#include <hip/hip_bf16.h>

#define TOK 16384
#define DIM 2048
#define RED 1024
#define KCR 5120   // 5 * 1024 stacked cross K
#define NPOW 6

typedef __attribute__((ext_vector_type(8))) short short8v;
typedef __attribute__((ext_vector_type(8))) unsigned short u16x8;
typedef __attribute__((ext_vector_type(4))) float f32x4;

__device__ __forceinline__ unsigned short f2bf(float f) {
    return __builtin_bit_cast(unsigned short, __float2bfloat16(f));
}
__device__ __forceinline__ float bf2f(unsigned short u) {
    union { unsigned u; float f; } v; v.u = ((unsigned)u) << 16; return v.f;
}

// async 16B/lane global->LDS (wave-uniform LDS base, HW adds lane*16)
__device__ __forceinline__ void glds16(const void* g, void* l) {
    __builtin_amdgcn_global_load_lds(
        (__attribute__((address_space(1))) void*)g,
        (__attribute__((address_space(3))) void*)l, 16, 0, 0);
}

// stage a 128x32 bf16 tile into linear LDS [128][4 slots of 16B], 8KB (fallback path)
__device__ __forceinline__ void stage_tile(const unsigned short* __restrict__ src,
                                           size_t rstride, int kb,
                                           unsigned char* smemBase, int wave, int lane)
{
    const int g = ((lane & 3) - ((lane >> 3) & 3)) & 3;
#pragma unroll
    for (int q = 0; q < 2; ++q) {
        const int c = 2 * wave + q;
        const int row = c * 16 + (lane >> 2);
        const unsigned short* gp = src + (size_t)row * rstride + kb + g * 8;
        glds16((const void*)gp, (void*)(smemBase + c * 1024));
    }
}

// ---------------------------------------------------------------------------
// Transpose + fp32->bf16 convert (weights)
// ---------------------------------------------------------------------------
__global__ __launch_bounds__(256)
void k_tcvt(const float* __restrict__ src, unsigned short* __restrict__ dst,
            int R, int C, int dstride, int slabR)
{
    __shared__ float tile[32][33];
    const int c0 = blockIdx.x * 32, r0 = blockIdx.y * 32;
    const int slab = blockIdx.z;
    src += (size_t)slab * R * C;
    const int x = threadIdx.x, y0 = threadIdx.y;
#pragma unroll
    for (int dy = 0; dy < 32; dy += 8)
        tile[y0 + dy][x] = src[(size_t)(r0 + y0 + dy) * C + c0 + x];
    __syncthreads();
#pragma unroll
    for (int dy = 0; dy < 32; dy += 8) {
        const int c = c0 + y0 + dy;
        dst[(size_t)c * dstride + slab * slabR + r0 + x] = f2bf(tile[x][y0 + dy]);
    }
}

// ---------------------------------------------------------------------------
// k_xcvt: X fp32 -> Xb bf16, pure BW
// ---------------------------------------------------------------------------
__global__ __launch_bounds__(256)
void k_xcvt(const float* __restrict__ X, unsigned short* __restrict__ Xb)
{
    const int N8 = TOK * DIM / 8;
    for (int i = blockIdx.x * blockDim.x + threadIdx.x; i < N8;
         i += gridDim.x * blockDim.x) {
        const float* p = X + (size_t)i * 8;
        float4 a = *(const float4*)p, b = *(const float4*)(p + 4);
        u16x8 o;
        o[0] = f2bf(a.x); o[1] = f2bf(a.y); o[2] = f2bf(a.z); o[3] = f2bf(a.w);
        o[4] = f2bf(b.x); o[5] = f2bf(b.y); o[6] = f2bf(b.z); o[7] = f2bf(b.w);
        *(u16x8*)(Xb + (size_t)i * 8) = o;
    }
}

// ---------------------------------------------------------------------------
// k_pow: pure-BW pass. H fp32 -> 5 bf16 power planes + POLYb bf16, coalesced.
// ---------------------------------------------------------------------------
__global__ __launch_bounds__(256)
void k_pow(const float* __restrict__ H, const float* __restrict__ coeffs,
           unsigned short* __restrict__ HP, unsigned short* __restrict__ POLYb)
{
    const int NOCT = TOK * RED / 8;
    for (int i = blockIdx.x * blockDim.x + threadIdx.x; i < NOCT;
         i += gridDim.x * blockDim.x) {
        const int row = i >> 7;
        const int col = (i & 127) << 3;
        const float* hp = H + (size_t)row * RED + col;
        float h[8];
        *(float4*)(h)     = *(const float4*)(hp);
        *(float4*)(h + 4) = *(const float4*)(hp + 4);
        float c[NPOW][8];
#pragma unroll
        for (int d = 0; d < NPOW; ++d) {
            *(float4*)(c[d])     = *(const float4*)(coeffs + d * RED + col);
            *(float4*)(c[d] + 4) = *(const float4*)(coeffs + d * RED + col + 4);
        }
        u16x8 o1, o2, o3, o4, o5, op;
#pragma unroll
        for (int j = 0; j < 8; ++j) {
            const float h1 = h[j], h2 = h1 * h1, h3 = h2 * h1;
            const float h4 = h2 * h2, h5 = h4 * h1, h6 = h3 * h3;
            const float poly = c[0][j] * h1 + c[1][j] * h2 + c[2][j] * h3 +
                               c[3][j] * h4 + c[4][j] * h5 + c[5][j] * h6;
            o1[j] = f2bf(h1); o2[j] = f2bf(h2); o3[j] = f2bf(h3);
            o4[j] = f2bf(h4); o5[j] = f2bf(h5); op[j] = f2bf(poly);
        }
        unsigned short* w = HP + (size_t)row * KCR + col;
        *(u16x8*)(w)           = o1;
        *(u16x8*)(w + RED)     = o2;
        *(u16x8*)(w + 2 * RED) = o3;
        *(u16x8*)(w + 3 * RED) = o4;
        *(u16x8*)(w + 4 * RED) = o5;
        *(u16x8*)(POLYb + (size_t)row * RED + col) = op;
    }
}

// ===========================================================================
// 256x256 / BK=64 / 8-wave / 4-phase counted-vmcnt GEMM template bits
// m201-style: two barriers per phase (pre-MFMA after ds_read+stage, post-MFMA)
// ===========================================================================
#define GEMM8_PREAMBLE(ASTRIDE, BSTRIDE)                                          \
    extern __shared__ unsigned char smem[];                                       \
    const int tid = threadIdx.x;                                                  \
    const int lane = tid & 63, wave = tid >> 6;                                   \
    const int wm_ = wave >> 2, wn_ = wave & 3;                                    \
    const int fr = lane & 15, lg = lane >> 4;                                     \
    const int g8 = (lane & 7) ^ (lane >> 3);                                      \
    const int srowoff = wave * 8 + (lane >> 3);                                   \
    const int ks0 = ((0 + lg) ^ (fr & 7)) * 16;                                   \
    const int ks1 = ((4 + lg) ^ (fr & 7)) * 16;                                   \
    const int frA = (wm_ * 128 + fr) * 128;                                       \
    const int frB = (wn_ * 64 + fr) * 128;

#define STAGE8G(src, stride, sweeprow, kb, dstbase)                               \
    glds16((const void*)((src) + (size_t)((sweeprow) + srowoff) * (stride) + (kb) + g8 * 8), \
           (void*)((dstbase) + (sweeprow) * 128 + wave * 1024))

#define GEMM8_TILE(stride_a, stride_b)                                            \
    {                                                                             \
        asm volatile("s_waitcnt vmcnt(2)\n\ts_barrier" ::: "memory");             \
        {                                                                         \
            short8v a00 = *(const short8v*)(Abuf + frA + 0 * 2048 + ks0);         \
            short8v a01 = *(const short8v*)(Abuf + frA + 0 * 2048 + ks1);         \
            short8v a10 = *(const short8v*)(Abuf + frA + 1 * 2048 + ks0);         \
            short8v a11 = *(const short8v*)(Abuf + frA + 1 * 2048 + ks1);         \
            _Pragma("unroll")                                                     \
            for (int ni = 0; ni < 4; ++ni) {                                      \
                bF[ni][0] = *(const short8v*)(Bbuf + frB + ni * 2048 + ks0);      \
                bF[ni][1] = *(const short8v*)(Bbuf + frB + ni * 2048 + ks1);      \
            }                                                                     \
            if (more) { STAGE8G(Bsrc, stride_b, 0, kb1, Bn);                      \
                        STAGE8G(Bsrc, stride_b, 64, kb1, Bn); }                   \
            __builtin_amdgcn_s_barrier();                                         \
            __builtin_amdgcn_s_setprio(1);                                        \
            _Pragma("unroll")                                                     \
            for (int ni = 0; ni < 4; ++ni) {                                      \
                acc[0][ni] = __builtin_amdgcn_mfma_f32_16x16x32_bf16(a00, bF[ni][0], acc[0][ni], 0, 0, 0); \
                acc[1][ni] = __builtin_amdgcn_mfma_f32_16x16x32_bf16(a10, bF[ni][0], acc[1][ni], 0, 0, 0); \
                acc[0][ni] = __builtin_amdgcn_mfma_f32_16x16x32_bf16(a01, bF[ni][1], acc[0][ni], 0, 0, 0); \
                acc[1][ni] = __builtin_amdgcn_mfma_f32_16x16x32_bf16(a11, bF[ni][1], acc[1][ni], 0, 0, 0); \
            }                                                                     \
            __builtin_amdgcn_s_setprio(0);                                        \
            __builtin_amdgcn_s_barrier();                                         \
        }                                                                         \
        {                                                                         \
            short8v a00 = *(const short8v*)(Abuf + frA + 2 * 2048 + ks0);         \
            short8v a01 = *(const short8v*)(Abuf + frA + 2 * 2048 + ks1);         \
            short8v a10 = *(const short8v*)(Abuf + frA + 3 * 2048 + ks0);         \
            short8v a11 = *(const short8v*)(Abuf + frA + 3 * 2048 + ks1);         \
            if (more) { STAGE8G(Bsrc, stride_b, 128, kb1, Bn);                    \
                        STAGE8G(Bsrc, stride_b, 192, kb1, Bn); }                  \
            __builtin_amdgcn_s_barrier();                                         \
            __builtin_amdgcn_s_setprio(1);                                        \
            _Pragma("unroll")                                                     \
            for (int ni = 0; ni < 4; ++ni) {                                      \
                acc[2][ni] = __builtin_amdgcn_mfma_f32_16x16x32_bf16(a00, bF[ni][0], acc[2][ni], 0, 0, 0); \
                acc[3][ni] = __builtin_amdgcn_mfma_f32_16x16x32_bf16(a10, bF[ni][0], acc[3][ni], 0, 0, 0); \
                acc[2][ni] = __builtin_amdgcn_mfma_f32_16x16x32_bf16(a01, bF[ni][1], acc[2][ni], 0, 0, 0); \
                acc[3][ni] = __builtin_amdgcn_mfma_f32_16x16x32_bf16(a11, bF[ni][1], acc[3][ni], 0, 0, 0); \
            }                                                                     \
            __builtin_amdgcn_s_setprio(0);                                        \
            __builtin_amdgcn_s_barrier();                                         \
        }                                                                         \
        if (more) { asm volatile("s_waitcnt vmcnt(4)\n\ts_barrier" ::: "memory"); } \
        else      { asm volatile("s_waitcnt vmcnt(0)\n\ts_barrier" ::: "memory"); } \
        {                                                                         \
            short8v a00 = *(const short8v*)(Abuf + frA + 4 * 2048 + ks0);         \
            short8v a01 = *(const short8v*)(Abuf + frA + 4 * 2048 + ks1);         \
            short8v a10 = *(const short8v*)(Abuf + frA + 5 * 2048 + ks0);         \
            short8v a11 = *(const short8v*)(Abuf + frA + 5 * 2048 + ks1);         \
            if (more) { STAGE8G(Asrc, stride_a, 0, kb1, An);                      \
                        STAGE8G(Asrc, stride_a, 128, kb1, An); }                  \
            __builtin_amdgcn_s_barrier();                                         \
            __builtin_amdgcn_s_setprio(1);                                        \
            _Pragma("unroll")                                                     \
            for (int ni = 0; ni < 4; ++ni) {                                      \
                acc[4][ni] = __builtin_amdgcn_mfma_f32_16x16x32_bf16(a00, bF[ni][0], acc[4][ni], 0, 0, 0); \
                acc[5][ni] = __builtin_amdgcn_mfma_f32_16x16x32_bf16(a10, bF[ni][0], acc[5][ni], 0, 0, 0); \
                acc[4][ni] = __builtin_amdgcn_mfma_f32_16x16x32_bf16(a01, bF[ni][1], acc[4][ni], 0, 0, 0); \
                acc[5][ni] = __builtin_amdgcn_mfma_f32_16x16x32_bf16(a11, bF[ni][1], acc[5][ni], 0, 0, 0); \
            }                                                                     \
            __builtin_amdgcn_s_setprio(0);                                        \
            __builtin_amdgcn_s_barrier();                                         \
        }                                                                         \
        {                                                                         \
            short8v a00 = *(const short8v*)(Abuf + frA + 6 * 2048 + ks0);         \
            short8v a01 = *(const short8v*)(Abuf + frA + 6 * 2048 + ks1);         \
            short8v a10 = *(const short8v*)(Abuf + frA + 7 * 2048 + ks0);         \
            short8v a11 = *(const short8v*)(Abuf + frA + 7 * 2048 + ks1);         \
            if (more) { STAGE8G(Asrc, stride_a, 64, kb1, An);                     \
                        STAGE8G(Asrc, stride_a, 192, kb1, An); }                  \
            __builtin_amdgcn_s_barrier();                                         \
            __builtin_amdgcn_s_setprio(1);                                        \
            _Pragma("unroll")                                                     \
            for (int ni = 0; ni < 4; ++ni) {                                      \
                acc[6][ni] = __builtin_amdgcn_mfma_f32_16x16x32_bf16(a00, bF[ni][0], acc[6][ni], 0, 0, 0); \
                acc[7][ni] = __builtin_amdgcn_mfma_f32_16x16x32_bf16(a10, bF[ni][0], acc[7][ni], 0, 0, 0); \
                acc[6][ni] = __builtin_amdgcn_mfma_f32_16x16x32_bf16(a01, bF[ni][1], acc[6][ni], 0, 0, 0); \
                acc[7][ni] = __builtin_amdgcn_mfma_f32_16x16x32_bf16(a11, bF[ni][1], acc[7][ni], 0, 0, 0); \
            }                                                                     \
            __builtin_amdgcn_s_setprio(0);                                        \
            __builtin_amdgcn_s_barrier();                                         \
        }                                                                         \
    }

#define GEMM8_PROLOGUE(stride_a, stride_b)                                        \
    {                                                                             \
        unsigned char* A0 = smem;                                                 \
        unsigned char* B0 = smem + 32768;                                         \
        STAGE8G(Bsrc, stride_b, 0,   0, B0); STAGE8G(Bsrc, stride_b, 64,  0, B0); \
        STAGE8G(Bsrc, stride_b, 128, 0, B0); STAGE8G(Bsrc, stride_b, 192, 0, B0); \
        STAGE8G(Asrc, stride_a, 0,   0, A0); STAGE8G(Asrc, stride_a, 128, 0, A0); \
        STAGE8G(Asrc, stride_a, 64,  0, A0); STAGE8G(Asrc, stride_a, 192, 0, A0); \
    }

#define GEMM8_EPI_SCATTER(q)                                                      \
    __syncthreads();                                                              \
    if (wm_ == ((q) >> 1)) {                                                      \
        const int mib = ((q) & 1) * 4;                                            \
        _Pragma("unroll")                                                         \
        for (int m = 0; m < 4; ++m)                                               \
            _Pragma("unroll")                                                     \
            for (int ni = 0; ni < 4; ++ni)                                        \
                _Pragma("unroll")                                                 \
                for (int j = 0; j < 4; ++j) {                                     \
                    const int trow = m * 16 + lg * 4 + j;                         \
                    const int tcol = (wn_ * 64 + ni * 16 + fr) ^ ((trow & 7) << 2); \
                    Tc[trow * 258 + tcol] = acc[mib + m][ni][j];                  \
                }                                                                 \
    }                                                                             \
    __syncthreads();

// ---------------------------------------------------------------------------
// k_down8: H = Xb(bf16) @ downT^T + down_b -> fp32 [TOK][RED]
// ---------------------------------------------------------------------------
__global__ __launch_bounds__(512, 1)
void k_down8(const unsigned short* __restrict__ Xb, const unsigned short* __restrict__ BT,
             const float* __restrict__ bias, float* __restrict__ H)
{
    GEMM8_PREAMBLE(DIM, DIM)
    const int bid = blockIdx.x;                    // 256 blocks
    const int vb = (bid & 7) * 32 + (bid >> 3);
    const int bm = (vb >> 2) * 256, bn = (vb & 3) * 256;
    const unsigned short* Asrc = Xb + (size_t)bm * DIM;
    const unsigned short* Bsrc = BT + (size_t)bn * DIM;

    f32x4 acc[8][4] = {};
    const int NT = DIM / 64;   // 32
    GEMM8_PROLOGUE(DIM, DIM)
    short8v bF[4][2];
    for (int t = 0; t < NT; ++t) {
        unsigned char* Abuf = smem + (t & 1) * 65536;
        unsigned char* Bbuf = Abuf + 32768;
        unsigned char* An   = smem + ((t + 1) & 1) * 65536;
        unsigned char* Bn   = An + 32768;
        const int kb1 = (t + 1) * 64;
        const bool more = (t + 1 < NT);
        GEMM8_TILE(DIM, DIM)
    }
    float* Tc = (float*)smem;
    for (int q = 0; q < 4; ++q) {
        GEMM8_EPI_SCATTER(q)
        const int trow = tid >> 3;
        const int c0 = (tid & 7) * 8;
        const int grow = bm + q * 64 + trow;
        const int colg = bn + c0;
        float* orow = H + (size_t)grow * RED + colg;
        const int sw = (trow & 7) << 2;
#pragma unroll
        for (int ch = 0; ch < 4; ++ch) {
            const int cc = c0 + ch * 64;
            float g[8];
            *(f32x4*)(g)     = *(const f32x4*)&Tc[trow * 258 + (cc ^ sw)];
            *(f32x4*)(g + 4) = *(const f32x4*)&Tc[trow * 258 + ((cc + 4) ^ sw)];
            f32x4 b0 = *(const f32x4*)(bias + colg + ch * 64);
            f32x4 b1 = *(const f32x4*)(bias + colg + ch * 64 + 4);
            f32x4 o0, o1;
#pragma unroll
            for (int k = 0; k < 4; ++k) { o0[k] = g[k] + b0[k]; o1[k] = g[4 + k] + b1[k]; }
            *(f32x4*)(orow + ch * 64)     = o0;
            *(f32x4*)(orow + ch * 64 + 4) = o1;
        }
    }
}

// ---------------------------------------------------------------------------
// k_cross8: stacked-K cross GEMM (K=5120), epilogue ACCb = bf16(poly+gemm*h)
// ---------------------------------------------------------------------------
__global__ __launch_bounds__(512, 1)
void k_cross8(const unsigned short* __restrict__ HP, const unsigned short* __restrict__ CT,
              const unsigned short* __restrict__ POLYb, unsigned short* __restrict__ ACCb)
{
    GEMM8_PREAMBLE(KCR, KCR)
    const int bid = blockIdx.x;                    // 256 blocks
    const int vb = (bid & 7) * 32 + (bid >> 3);
    const int bm = (vb >> 2) * 256, bn = (vb & 3) * 256;
    const unsigned short* Asrc = HP + (size_t)bm * KCR;
    const unsigned short* Bsrc = CT + (size_t)bn * KCR;

    f32x4 acc[8][4] = {};
    const int NT = KCR / 64;   // 80
    GEMM8_PROLOGUE(KCR, KCR)
    short8v bF[4][2];
    for (int t = 0; t < NT; ++t) {
        unsigned char* Abuf = smem + (t & 1) * 65536;
        unsigned char* Bbuf = Abuf + 32768;
        unsigned char* An   = smem + ((t + 1) & 1) * 65536;
        unsigned char* Bn   = An + 32768;
        const int kb1 = (t + 1) * 64;
        const bool more = (t + 1 < NT);
        GEMM8_TILE(KCR, KCR)
    }
    float* Tc = (float*)smem;
    for (int q = 0; q < 4; ++q) {
        GEMM8_EPI_SCATTER(q)
        const int trow = tid >> 3;
        const int c0 = (tid & 7) * 8;
        const int grow = bm + q * 64 + trow;
        const unsigned short* hrow = HP + (size_t)grow * KCR + bn + c0;
        const unsigned short* prow = POLYb + (size_t)grow * RED + bn + c0;
        unsigned short* orow = ACCb + (size_t)grow * RED + bn + c0;
        const int sw = (trow & 7) << 2;
#pragma unroll
        for (int ch = 0; ch < 4; ++ch) {
            const int cc = c0 + ch * 64;
            float g[8];
            *(f32x4*)(g)     = *(const f32x4*)&Tc[trow * 258 + (cc ^ sw)];
            *(f32x4*)(g + 4) = *(const f32x4*)&Tc[trow * 258 + ((cc + 4) ^ sw)];
            u16x8 hh = *(const u16x8*)(hrow + ch * 64);
            u16x8 ppv = *(const u16x8*)(prow + ch * 64);
            u16x8 ov;
#pragma unroll
            for (int k = 0; k < 8; ++k)
                ov[k] = f2bf(bf2f(ppv[k]) + g[k] * bf2f(hh[k]));
            *(u16x8*)(orow + ch * 64) = ov;
        }
    }
}

// ---------------------------------------------------------------------------
// k_up8: OUT = ACCb(bf16) @ upT^T + up_b + X -> fp32 [TOK][DIM]
// ---------------------------------------------------------------------------
__global__ __launch_bounds__(512, 1)
void k_up8(const unsigned short* __restrict__ A, const unsigned short* __restrict__ BT,
           const float* __restrict__ bias, const float* __restrict__ X,
           float* __restrict__ OUT)
{
    GEMM8_PREAMBLE(RED, RED)
    const int bid = blockIdx.x;                    // 512 blocks
    const int vb = (bid & 7) * 64 + (bid >> 3);
    const int bm = (vb >> 3) * 256, bn = (vb & 7) * 256;
    const unsigned short* Asrc = A + (size_t)bm * RED;
    const unsigned short* Bsrc = BT + (size_t)bn * RED;

    f32x4 acc[8][4] = {};
    const int NT = RED / 64;   // 16
    GEMM8_PROLOGUE(RED, RED)
    short8v bF[4][2];
    for (int t = 0; t < NT; ++t) {
        unsigned char* Abuf = smem + (t & 1) * 65536;
        unsigned char* Bbuf = Abuf + 32768;
        unsigned char* An   = smem + ((t + 1) & 1) * 65536;
        unsigned char* Bn   = An + 32768;
        const int kb1 = (t + 1) * 64;
        const bool more = (t + 1 < NT);
        GEMM8_TILE(RED, RED)
    }
    float* Tc = (float*)smem;
    for (int q = 0; q < 4; ++q) {
        GEMM8_EPI_SCATTER(q)
        const int trow = tid >> 3;
        const int c0 = (tid & 7) * 8;
        const int grow = bm + q * 64 + trow;
        const int colg = bn + c0;
        const float* xrow = X + (size_t)grow * DIM + colg;
        float* orow = OUT + (size_t)grow * DIM + colg;
        const int sw = (trow & 7) << 2;
#pragma unroll
        for (int ch = 0; ch < 4; ++ch) {
            const int cc = c0 + ch * 64;
            float g[8];
            *(f32x4*)(g)     = *(const f32x4*)&Tc[trow * 258 + (cc ^ sw)];
            *(f32x4*)(g + 4) = *(const f32x4*)&Tc[trow * 258 + ((cc + 4) ^ sw)];
            f32x4 b0 = *(const f32x4*)(bias + colg + ch * 64);
            f32x4 b1 = *(const f32x4*)(bias + colg + ch * 64 + 4);
            f32x4 x0 = *(const f32x4*)(xrow + ch * 64);
            f32x4 x1 = *(const f32x4*)(xrow + ch * 64 + 4);
            f32x4 o0, o1;
#pragma unroll
            for (int k = 0; k < 4; ++k) {
                o0[k] = g[k] + b0[k] + x0[k];
                o1[k] = g[4 + k] + b1[k] + x1[k];
            }
            *(f32x4*)(orow + ch * 64)     = o0;
            *(f32x4*)(orow + ch * 64 + 4) = o1;
        }
    }
}

// ===========================================================================
// FALLBACK PATH (round-5 verbatim, used when ws_size is too small)
// ===========================================================================
__global__ __launch_bounds__(256)
void k_downS(const float* __restrict__ X, const unsigned short* __restrict__ BT,
             const float* __restrict__ bias, float* __restrict__ H)
{
    __shared__ unsigned short As[128][40];
    __shared__ unsigned short Bs[128][40];
    const int tid = threadIdx.x;
    const int bid = blockIdx.x;
    const int bm = (bid >> 3) * 128, bn = (bid & 7) * 128;
    const int srow = tid >> 1, skq = (tid & 1) << 4;
    const int lane = tid & 63, wave = tid >> 6;
    const int wm = (wave >> 1) << 6, wn = (wave & 1) << 6;
    const int fr = lane & 15, lg = lane >> 4;

    f32x4 acc[4][4] = {};
    const float* ap = X + (size_t)(bm + srow) * DIM + skq;
    const unsigned short* bp = BT + (size_t)(bn + srow) * DIM + skq;

    for (int kb = 0; kb < DIM; kb += 32) {
        float4 a0 = *(const float4*)(ap + kb);
        float4 a1 = *(const float4*)(ap + kb + 4);
        float4 a2 = *(const float4*)(ap + kb + 8);
        float4 a3 = *(const float4*)(ap + kb + 12);
        u16x8 b0 = *(const u16x8*)(bp + kb);
        u16x8 b1 = *(const u16x8*)(bp + kb + 8);
        u16x8 p0, p1;
        p0[0] = f2bf(a0.x); p0[1] = f2bf(a0.y); p0[2] = f2bf(a0.z); p0[3] = f2bf(a0.w);
        p0[4] = f2bf(a1.x); p0[5] = f2bf(a1.y); p0[6] = f2bf(a1.z); p0[7] = f2bf(a1.w);
        p1[0] = f2bf(a2.x); p1[1] = f2bf(a2.y); p1[2] = f2bf(a2.z); p1[3] = f2bf(a2.w);
        p1[4] = f2bf(a3.x); p1[5] = f2bf(a3.y); p1[6] = f2bf(a3.z); p1[7] = f2bf(a3.w);
        __syncthreads();
        *(u16x8*)&As[srow][skq]     = p0;
        *(u16x8*)&As[srow][skq + 8] = p1;
        *(u16x8*)&Bs[srow][skq]     = b0;
        *(u16x8*)&Bs[srow][skq + 8] = b1;
        __syncthreads();
        short8v af[4], bfv[4];
#pragma unroll
        for (int mi = 0; mi < 4; ++mi)
            af[mi] = *(const short8v*)&As[wm + mi * 16 + fr][lg * 8];
#pragma unroll
        for (int ni = 0; ni < 4; ++ni)
            bfv[ni] = *(const short8v*)&Bs[wn + ni * 16 + fr][lg * 8];
#pragma unroll
        for (int mi = 0; mi < 4; ++mi)
#pragma unroll
            for (int ni = 0; ni < 4; ++ni)
                acc[mi][ni] = __builtin_amdgcn_mfma_f32_16x16x32_bf16(
                    af[mi], bfv[ni], acc[mi][ni], 0, 0, 0);
    }
#pragma unroll
    for (int ni = 0; ni < 4; ++ni) {
        const int col = bn + wn + ni * 16 + fr;
        const float bv = bias[col];
#pragma unroll
        for (int mi = 0; mi < 4; ++mi)
#pragma unroll
            for (int j = 0; j < 4; ++j) {
                const int row = bm + wm + mi * 16 + lg * 4 + j;
                H[(size_t)row * RED + col] = acc[mi][ni][j] + bv;
            }
    }
}

__global__ __launch_bounds__(256)
void k_crossS(const float* __restrict__ H, const unsigned short* __restrict__ CT,
              const float* __restrict__ coeffs, unsigned short* __restrict__ ACCb)
{
    __shared__ unsigned short As[128][84];
    __shared__ unsigned short Bs[128][84];
    const int tid = threadIdx.x;
    const int bid = blockIdx.x;
    const int bm = (bid >> 3) * 128;
    const int bn = (bid & 7) * 128;
    const int srow = tid >> 1, sc = (tid & 1) << 4;
    const int lane = tid & 63, wave = tid >> 6;
    const int wm = (wave >> 1) << 6, wn = (wave & 1) << 6;
    const int fr = lane & 15, lg = lane >> 4;

    f32x4 acc[4][4] = {};
    const float* hp = H + (size_t)(bm + srow) * RED + sc;
    const unsigned short* bp = CT + (size_t)(bn + srow) * KCR + sc;

    for (int g = 0; g < 3; ++g) {
        const bool two = (g < 2);
        const unsigned short* bp0 = bp + (2 * g) * RED;
        const unsigned short* bp1 = bp + (2 * g + 1) * RED;
        for (int rb = 0; rb < RED; rb += 32) {
            float4 h0 = *(const float4*)(hp + rb);
            float4 h1 = *(const float4*)(hp + rb + 4);
            float4 h2 = *(const float4*)(hp + rb + 8);
            float4 h3 = *(const float4*)(hp + rb + 12);
            u16x8 b00 = *(const u16x8*)(bp0 + rb);
            u16x8 b01 = *(const u16x8*)(bp0 + rb + 8);
            u16x8 b10 = {}, b11 = {};
            if (two) {
                b10 = *(const u16x8*)(bp1 + rb);
                b11 = *(const u16x8*)(bp1 + rb + 8);
            }
            const float v[16] = {h0.x, h0.y, h0.z, h0.w, h1.x, h1.y, h1.z, h1.w,
                                 h2.x, h2.y, h2.z, h2.w, h3.x, h3.y, h3.z, h3.w};
            u16x8 pa0, pa1, pb0, pb1;
#pragma unroll
            for (int j = 0; j < 16; ++j) {
                const float x = v[j];
                float a, b;
                if (g == 0)      { a = x;                  b = x * x; }
                else if (g == 1) { const float x2 = x * x; a = x2 * x;      b = x2 * x2; }
                else             { const float x2 = x * x; a = x2 * x2 * x; b = 0.f; }
                const unsigned short ua = f2bf(a), ub = f2bf(b);
                if (j < 8) { pa0[j] = ua;     pb0[j] = ub; }
                else       { pa1[j - 8] = ua; pb1[j - 8] = ub; }
            }
            __syncthreads();
            *(u16x8*)&As[srow][sc]     = pa0;
            *(u16x8*)&As[srow][sc + 8] = pa1;
            *(u16x8*)&Bs[srow][sc]     = b00;
            *(u16x8*)&Bs[srow][sc + 8] = b01;
            if (two) {
                *(u16x8*)&As[srow][40 + sc]     = pb0;
                *(u16x8*)&As[srow][40 + sc + 8] = pb1;
                *(u16x8*)&Bs[srow][40 + sc]     = b10;
                *(u16x8*)&Bs[srow][40 + sc + 8] = b11;
            }
            __syncthreads();
            {
                short8v afv[4], bfv[4];
#pragma unroll
                for (int mi = 0; mi < 4; ++mi)
                    afv[mi] = *(const short8v*)&As[wm + mi * 16 + fr][lg * 8];
#pragma unroll
                for (int ni = 0; ni < 4; ++ni)
                    bfv[ni] = *(const short8v*)&Bs[wn + ni * 16 + fr][lg * 8];
#pragma unroll
                for (int mi = 0; mi < 4; ++mi)
#pragma unroll
                    for (int ni = 0; ni < 4; ++ni)
                        acc[mi][ni] = __builtin_amdgcn_mfma_f32_16x16x32_bf16(
                            afv[mi], bfv[ni], acc[mi][ni], 0, 0, 0);
            }
            if (two) {
                short8v afv[4], bfv[4];
#pragma unroll
                for (int mi = 0; mi < 4; ++mi)
                    afv[mi] = *(const short8v*)&As[wm + mi * 16 + fr][40 + lg * 8];
#pragma unroll
                for (int ni = 0; ni < 4; ++ni)
                    bfv[ni] = *(const short8v*)&Bs[wn + ni * 16 + fr][40 + lg * 8];
#pragma unroll
                for (int mi = 0; mi < 4; ++mi)
#pragma unroll
                    for (int ni = 0; ni < 4; ++ni)
                        acc[mi][ni] = __builtin_amdgcn_mfma_f32_16x16x32_bf16(
                            afv[mi], bfv[ni], acc[mi][ni], 0, 0, 0);
            }
        }
    }
#pragma unroll
    for (int ni = 0; ni < 4; ++ni) {
        const int col = bn + wn + ni * 16 + fr;
        float cf[NPOW];
#pragma unroll
        for (int d = 0; d < NPOW; ++d) cf[d] = coeffs[d * RED + col];
#pragma unroll
        for (int mi = 0; mi < 4; ++mi)
#pragma unroll
            for (int j = 0; j < 4; ++j) {
                const int row = bm + wm + mi * 16 + lg * 4 + j;
                const float h = H[(size_t)row * RED + col];
                float poly = 0.f, pw = h;
#pragma unroll
                for (int d = 0; d < NPOW; ++d) { poly += pw * cf[d]; pw *= h; }
                ACCb[(size_t)row * RED + col] = f2bf(poly + acc[mi][ni][j] * h);
            }
    }
}

__global__ __launch_bounds__(256)
void k_upS(const unsigned short* __restrict__ A, const unsigned short* __restrict__ BT,
           const float* __restrict__ bias, const float* __restrict__ X,
           float* __restrict__ OUT)
{
    __shared__ unsigned short As[128][40];
    __shared__ unsigned short Bs[128][40];
    const int tid = threadIdx.x;
    const int bid = blockIdx.x;
    const int bm = (bid >> 4) * 128, bn = (bid & 15) * 128;
    const int srow = tid >> 1, skq = (tid & 1) << 4;
    const int lane = tid & 63, wave = tid >> 6;
    const int wm = (wave >> 1) << 6, wn = (wave & 1) << 6;
    const int fr = lane & 15, lg = lane >> 4;

    f32x4 acc[4][4] = {};
    const unsigned short* ap = A + (size_t)(bm + srow) * RED + skq;
    const unsigned short* bp = BT + (size_t)(bn + srow) * RED + skq;

    for (int kb = 0; kb < RED; kb += 32) {
        u16x8 a0 = *(const u16x8*)(ap + kb);
        u16x8 a1 = *(const u16x8*)(ap + kb + 8);
        u16x8 b0 = *(const u16x8*)(bp + kb);
        u16x8 b1 = *(const u16x8*)(bp + kb + 8);
        __syncthreads();
        *(u16x8*)&As[srow][skq]     = a0;
        *(u16x8*)&As[srow][skq + 8] = a1;
        *(u16x8*)&Bs[srow][skq]     = b0;
        *(u16x8*)&Bs[srow][skq + 8] = b1;
        __syncthreads();
        short8v af[4], bfv[4];
#pragma unroll
        for (int mi = 0; mi < 4; ++mi)
            af[mi] = *(const short8v*)&As[wm + mi * 16 + fr][lg * 8];
#pragma unroll
        for (int ni = 0; ni < 4; ++ni)
            bfv[ni] = *(const short8v*)&Bs[wn + ni * 16 + fr][lg * 8];
#pragma unroll
        for (int mi = 0; mi < 4; ++mi)
#pragma unroll
            for (int ni = 0; ni < 4; ++ni)
                acc[mi][ni] = __builtin_amdgcn_mfma_f32_16x16x32_bf16(
                    af[mi], bfv[ni], acc[mi][ni], 0, 0, 0);
    }
#pragma unroll
    for (int ni = 0; ni < 4; ++ni) {
        const int col = bn + wn + ni * 16 + fr;
        const float bv = bias[col];
#pragma unroll
        for (int mi = 0; mi < 4; ++mi)
#pragma unroll
            for (int j = 0; j < 4; ++j) {
                const int row = bm + wm + mi * 16 + lg * 4 + j;
                OUT[(size_t)row * DIM + col] =
                    acc[mi][ni][j] + bv + X[(size_t)row * DIM + col];
            }
    }
}

extern "C" void kernel_launch(void* const* d_in, const int* in_sizes, int n_in,
                              void* d_out, int out_size, void* d_ws, size_t ws_size,
                              hipStream_t stream) {
    const float* x      = (const float*)d_in[0];
    const float* down_w = (const float*)d_in[1];
    const float* down_b = (const float*)d_in[2];
    const float* coeffs = (const float*)d_in[3];
    const float* cross  = (const float*)d_in[4];
    const float* up_w   = (const float*)d_in[5];
    const float* up_b   = (const float*)d_in[6];
    float* out = (float*)d_out;
    unsigned char* w = (unsigned char*)d_ws;

    const size_t needF = 287309824ull;   // known-passing fast-path footprint

    if (ws_size >= needF) {
        // r18 layout: H @0 (64M, dead after k_pow; ACCb aliases it);
        // Xb @64M (dead after k_down8; HP aliases it, written by k_pow)
        float*          H      = (float*)w;
        unsigned short* ACCb   = (unsigned short*)w;                      // alias (H dead)
        unsigned short* Xb     = (unsigned short*)(w + 67108864ull);
        unsigned short* HP     = (unsigned short*)(w + 67108864ull);      // alias (Xb dead)
        unsigned short* POLYb  = (unsigned short*)(w + 234881024ull);     // 32M
        unsigned short* downT  = (unsigned short*)(w + 268435456ull);     // 4M
        unsigned short* crossT = (unsigned short*)(w + 272629760ull);     // 10M
        unsigned short* upT    = (unsigned short*)(w + 283115520ull);     // 4M

        hipFuncSetAttribute((const void*)k_down8,
                            hipFuncAttributeMaxDynamicSharedMemorySize, 131072);
        hipFuncSetAttribute((const void*)k_cross8,
                            hipFuncAttributeMaxDynamicSharedMemorySize, 131072);
        hipFuncSetAttribute((const void*)k_up8,
                            hipFuncAttributeMaxDynamicSharedMemorySize, 131072);

        k_tcvt<<<dim3(RED / 32, DIM / 32, 1), dim3(32, 8), 0, stream>>>(
            down_w, downT, DIM, RED, DIM, 0);
        k_tcvt<<<dim3(RED / 32, RED / 32, 5), dim3(32, 8), 0, stream>>>(
            cross, crossT, RED, RED, KCR, RED);
        k_tcvt<<<dim3(DIM / 32, RED / 32, 1), dim3(32, 8), 0, stream>>>(
            up_w, upT, RED, DIM, RED, 0);

        k_xcvt  <<<2048, 256, 0, stream>>>(x, Xb);
        k_down8 <<<TOK / 256 * (RED / 256), 512, 131072, stream>>>(
            Xb, downT, down_b, H);
        k_pow   <<<2048, 256, 0, stream>>>(H, coeffs, HP, POLYb);
        k_cross8<<<TOK / 256 * (RED / 256), 512, 131072, stream>>>(
            HP, crossT, POLYb, ACCb);
        k_up8   <<<TOK / 256 * (DIM / 256), 512, 131072, stream>>>(
            ACCb, upT, up_b, x, out);
    } else {
        float*          H      = (float*)w;
        unsigned short* ACCb   = (unsigned short*)(w + 67108864ull);
        unsigned short* downT  = (unsigned short*)(w + 100663296ull);
        unsigned short* crossT = (unsigned short*)(w + 104857600ull);
        unsigned short* upT    = (unsigned short*)(w + 115343360ull);

        k_tcvt<<<dim3(RED / 32, DIM / 32, 1), dim3(32, 8), 0, stream>>>(
            down_w, downT, DIM, RED, DIM, 0);
        k_tcvt<<<dim3(RED / 32, RED / 32, 5), dim3(32, 8), 0, stream>>>(
            cross, crossT, RED, RED, KCR, RED);
        k_tcvt<<<dim3(DIM / 32, RED / 32, 1), dim3(32, 8), 0, stream>>>(
            up_w, upT, RED, DIM, RED, 0);

        k_downS <<<TOK / 128 * (RED / 128), 256, 0, stream>>>(x, downT, down_b, H);
        k_crossS<<<TOK / 128 * (RED / 128), 256, 0, stream>>>(H, crossT, coeffs, ACCb);
        k_upS   <<<TOK / 128 * (DIM / 128), 256, 0, stream>>>(ACCb, upT, up_b, x, out);
    }
}

// Round 25
// 406.307 us; speedup vs baseline: 1.0345x; 1.0345x over previous
//
#include <hip/hip_runtime.h>
#include <hip/hip_bf16.h>

#define TOK 16384
#define DIM 2048
#define RED 1024
#define KCR 5120   // 5 * 1024 stacked cross K
#define NPOW 6

typedef __attribute__((ext_vector_type(8))) short short8v;
typedef __attribute__((ext_vector_type(8))) unsigned short u16x8;
typedef __attribute__((ext_vector_type(4))) float f32x4;

__device__ __forceinline__ unsigned short f2bf(float f) {
    return __builtin_bit_cast(unsigned short, __float2bfloat16(f));
}
__device__ __forceinline__ float bf2f(unsigned short u) {
    union { unsigned u; float f; } v; v.u = ((unsigned)u) << 16; return v.f;
}

// async 16B/lane global->LDS (wave-uniform LDS base, HW adds lane*16)
__device__ __forceinline__ void glds16(const void* g, void* l) {
    __builtin_amdgcn_global_load_lds(
        (__attribute__((address_space(1))) void*)g,
        (__attribute__((address_space(3))) void*)l, 16, 0, 0);
}

// stage a 128x32 bf16 tile into linear LDS [128][4 slots of 16B], 8KB (fallback path)
__device__ __forceinline__ void stage_tile(const unsigned short* __restrict__ src,
                                           size_t rstride, int kb,
                                           unsigned char* smemBase, int wave, int lane)
{
    const int g = ((lane & 3) - ((lane >> 3) & 3)) & 3;
#pragma unroll
    for (int q = 0; q < 2; ++q) {
        const int c = 2 * wave + q;
        const int row = c * 16 + (lane >> 2);
        const unsigned short* gp = src + (size_t)row * rstride + kb + g * 8;
        glds16((const void*)gp, (void*)(smemBase + c * 1024));
    }
}

// ---------------------------------------------------------------------------
// Transpose + fp32->bf16 convert body (shared by k_tcvt and k_prep)
// ---------------------------------------------------------------------------
__device__ __forceinline__ void tcvt_body(float (*tile)[33],
    const float* __restrict__ src, unsigned short* __restrict__ dst,
    int R, int C, int dstride, int slabR, int bx, int by, int slab, int tid)
{
    const int c0 = bx * 32, r0 = by * 32;
    src += (size_t)slab * R * C;
    const int x = tid & 31, y0 = tid >> 5;
#pragma unroll
    for (int dy = 0; dy < 32; dy += 8)
        tile[y0 + dy][x] = src[(size_t)(r0 + y0 + dy) * C + c0 + x];
    __syncthreads();
#pragma unroll
    for (int dy = 0; dy < 32; dy += 8) {
        const int c = c0 + y0 + dy;
        dst[(size_t)c * dstride + (size_t)slab * slabR + r0 + x] = f2bf(tile[x][y0 + dy]);
    }
}

__global__ __launch_bounds__(256)
void k_tcvt(const float* __restrict__ src, unsigned short* __restrict__ dst,
            int R, int C, int dstride, int slabR)
{
    __shared__ float tile[32][33];
    tcvt_body(tile, src, dst, R, C, dstride, slabR,
              blockIdx.x, blockIdx.y, blockIdx.z,
              threadIdx.y * 32 + threadIdx.x);
}

// ---------------------------------------------------------------------------
// k_prep: fused prep pass — xcvt (X fp32 -> Xb bf16) + 3 weight transposes.
// blockIdx ranges: [0,2048) xcvt, [2048,4096) downT, [4096,9216) crossT,
// [9216,11264) upT. Branch is block-uniform.
// ---------------------------------------------------------------------------
__global__ __launch_bounds__(256)
void k_prep(const float* __restrict__ X, unsigned short* __restrict__ Xb,
            const float* __restrict__ down_w, unsigned short* __restrict__ downT,
            const float* __restrict__ cross, unsigned short* __restrict__ crossT,
            const float* __restrict__ up_w, unsigned short* __restrict__ upT)
{
    __shared__ float tile[32][33];
    const int b = blockIdx.x;
    const int tid = threadIdx.x;
    if (b < 2048) {
        const int base = b * 2048;
#pragma unroll
        for (int k = 0; k < 8; ++k) {
            const int i = base + k * 256 + tid;
            const float* p = X + (size_t)i * 8;
            float4 a = *(const float4*)p, c4 = *(const float4*)(p + 4);
            u16x8 o;
            o[0] = f2bf(a.x);  o[1] = f2bf(a.y);  o[2] = f2bf(a.z);  o[3] = f2bf(a.w);
            o[4] = f2bf(c4.x); o[5] = f2bf(c4.y); o[6] = f2bf(c4.z); o[7] = f2bf(c4.w);
            *(u16x8*)(Xb + (size_t)i * 8) = o;
        }
    } else if (b < 4096) {
        const int idx = b - 2048;                    // grid (32, 64)
        tcvt_body(tile, down_w, downT, DIM, RED, DIM, 0, idx & 31, idx >> 5, 0, tid);
    } else if (b < 9216) {
        const int idx = b - 4096;                    // grid (32, 32, 5)
        tcvt_body(tile, cross, crossT, RED, RED, KCR, RED,
                  idx & 31, (idx >> 5) & 31, idx >> 10, tid);
    } else {
        const int idx = b - 9216;                    // grid (64, 32)
        tcvt_body(tile, up_w, upT, RED, DIM, RED, 0, idx & 63, idx >> 6, 0, tid);
    }
}

// ---------------------------------------------------------------------------
// k_pow: pure-BW pass. H fp32 -> 5 bf16 power planes + POLYb bf16, coalesced.
// ---------------------------------------------------------------------------
__global__ __launch_bounds__(256)
void k_pow(const float* __restrict__ H, const float* __restrict__ coeffs,
           unsigned short* __restrict__ HP, unsigned short* __restrict__ POLYb)
{
    const int NOCT = TOK * RED / 8;
    for (int i = blockIdx.x * blockDim.x + threadIdx.x; i < NOCT;
         i += gridDim.x * blockDim.x) {
        const int row = i >> 7;
        const int col = (i & 127) << 3;
        const float* hp = H + (size_t)row * RED + col;
        float h[8];
        *(float4*)(h)     = *(const float4*)(hp);
        *(float4*)(h + 4) = *(const float4*)(hp + 4);
        float c[NPOW][8];
#pragma unroll
        for (int d = 0; d < NPOW; ++d) {
            *(float4*)(c[d])     = *(const float4*)(coeffs + d * RED + col);
            *(float4*)(c[d] + 4) = *(const float4*)(coeffs + d * RED + col + 4);
        }
        u16x8 o1, o2, o3, o4, o5, op;
#pragma unroll
        for (int j = 0; j < 8; ++j) {
            const float h1 = h[j], h2 = h1 * h1, h3 = h2 * h1;
            const float h4 = h2 * h2, h5 = h4 * h1, h6 = h3 * h3;
            const float poly = c[0][j] * h1 + c[1][j] * h2 + c[2][j] * h3 +
                               c[3][j] * h4 + c[4][j] * h5 + c[5][j] * h6;
            o1[j] = f2bf(h1); o2[j] = f2bf(h2); o3[j] = f2bf(h3);
            o4[j] = f2bf(h4); o5[j] = f2bf(h5); op[j] = f2bf(poly);
        }
        unsigned short* w = HP + (size_t)row * KCR + col;
        *(u16x8*)(w)           = o1;
        *(u16x8*)(w + RED)     = o2;
        *(u16x8*)(w + 2 * RED) = o3;
        *(u16x8*)(w + 3 * RED) = o4;
        *(u16x8*)(w + 4 * RED) = o5;
        *(u16x8*)(POLYb + (size_t)row * RED + col) = op;
    }
}

// ===========================================================================
// 256x256 / BK=64 / 8-wave / 4-phase counted-vmcnt GEMM template bits
// ===========================================================================
#define GEMM8_PREAMBLE(ASTRIDE, BSTRIDE)                                          \
    extern __shared__ unsigned char smem[];                                       \
    const int tid = threadIdx.x;                                                  \
    const int lane = tid & 63, wave = tid >> 6;                                   \
    const int wm_ = wave >> 2, wn_ = wave & 3;                                    \
    const int fr = lane & 15, lg = lane >> 4;                                     \
    const int g8 = (lane & 7) ^ (lane >> 3);                                      \
    const int srowoff = wave * 8 + (lane >> 3);                                   \
    const int ks0 = ((0 + lg) ^ (fr & 7)) * 16;                                   \
    const int ks1 = ((4 + lg) ^ (fr & 7)) * 16;                                   \
    const int frA = (wm_ * 128 + fr) * 128;                                       \
    const int frB = (wn_ * 64 + fr) * 128;

#define STAGE8G(src, stride, sweeprow, kb, dstbase)                               \
    glds16((const void*)((src) + (size_t)((sweeprow) + srowoff) * (stride) + (kb) + g8 * 8), \
           (void*)((dstbase) + (sweeprow) * 128 + wave * 1024))

#define GEMM8_TILE(stride_a, stride_b)                                            \
    {                                                                             \
        asm volatile("s_waitcnt vmcnt(2)\n\ts_barrier" ::: "memory");             \
        {                                                                         \
            short8v a00 = *(const short8v*)(Abuf + frA + 0 * 2048 + ks0);         \
            short8v a01 = *(const short8v*)(Abuf + frA + 0 * 2048 + ks1);         \
            short8v a10 = *(const short8v*)(Abuf + frA + 1 * 2048 + ks0);         \
            short8v a11 = *(const short8v*)(Abuf + frA + 1 * 2048 + ks1);         \
            _Pragma("unroll")                                                     \
            for (int ni = 0; ni < 4; ++ni) {                                      \
                bF[ni][0] = *(const short8v*)(Bbuf + frB + ni * 2048 + ks0);      \
                bF[ni][1] = *(const short8v*)(Bbuf + frB + ni * 2048 + ks1);      \
            }                                                                     \
            if (more) { STAGE8G(Bsrc, stride_b, 0, kb1, Bn);                      \
                        STAGE8G(Bsrc, stride_b, 64, kb1, Bn); }                   \
            __builtin_amdgcn_s_setprio(1);                                        \
            _Pragma("unroll")                                                     \
            for (int ni = 0; ni < 4; ++ni) {                                      \
                acc[0][ni] = __builtin_amdgcn_mfma_f32_16x16x32_bf16(a00, bF[ni][0], acc[0][ni], 0, 0, 0); \
                acc[1][ni] = __builtin_amdgcn_mfma_f32_16x16x32_bf16(a10, bF[ni][0], acc[1][ni], 0, 0, 0); \
                acc[0][ni] = __builtin_amdgcn_mfma_f32_16x16x32_bf16(a01, bF[ni][1], acc[0][ni], 0, 0, 0); \
                acc[1][ni] = __builtin_amdgcn_mfma_f32_16x16x32_bf16(a11, bF[ni][1], acc[1][ni], 0, 0, 0); \
            }                                                                     \
            __builtin_amdgcn_s_setprio(0);                                        \
        }                                                                         \
        {                                                                         \
            short8v a00 = *(const short8v*)(Abuf + frA + 2 * 2048 + ks0);         \
            short8v a01 = *(const short8v*)(Abuf + frA + 2 * 2048 + ks1);         \
            short8v a10 = *(const short8v*)(Abuf + frA + 3 * 2048 + ks0);         \
            short8v a11 = *(const short8v*)(Abuf + frA + 3 * 2048 + ks1);         \
            if (more) { STAGE8G(Bsrc, stride_b, 128, kb1, Bn);                    \
                        STAGE8G(Bsrc, stride_b, 192, kb1, Bn); }                  \
            __builtin_amdgcn_s_setprio(1);                                        \
            _Pragma("unroll")                                                     \
            for (int ni = 0; ni < 4; ++ni) {                                      \
                acc[2][ni] = __builtin_amdgcn_mfma_f32_16x16x32_bf16(a00, bF[ni][0], acc[2][ni], 0, 0, 0); \
                acc[3][ni] = __builtin_amdgcn_mfma_f32_16x16x32_bf16(a10, bF[ni][0], acc[3][ni], 0, 0, 0); \
                acc[2][ni] = __builtin_amdgcn_mfma_f32_16x16x32_bf16(a01, bF[ni][1], acc[2][ni], 0, 0, 0); \
                acc[3][ni] = __builtin_amdgcn_mfma_f32_16x16x32_bf16(a11, bF[ni][1], acc[3][ni], 0, 0, 0); \
            }                                                                     \
            __builtin_amdgcn_s_setprio(0);                                        \
        }                                                                         \
        if (more) { asm volatile("s_waitcnt vmcnt(4)\n\ts_barrier" ::: "memory"); } \
        else      { asm volatile("s_waitcnt vmcnt(0)\n\ts_barrier" ::: "memory"); } \
        {                                                                         \
            short8v a00 = *(const short8v*)(Abuf + frA + 4 * 2048 + ks0);         \
            short8v a01 = *(const short8v*)(Abuf + frA + 4 * 2048 + ks1);         \
            short8v a10 = *(const short8v*)(Abuf + frA + 5 * 2048 + ks0);         \
            short8v a11 = *(const short8v*)(Abuf + frA + 5 * 2048 + ks1);         \
            if (more) { STAGE8G(Asrc, stride_a, 0, kb1, An);                      \
                        STAGE8G(Asrc, stride_a, 128, kb1, An); }                  \
            __builtin_amdgcn_s_setprio(1);                                        \
            _Pragma("unroll")                                                     \
            for (int ni = 0; ni < 4; ++ni) {                                      \
                acc[4][ni] = __builtin_amdgcn_mfma_f32_16x16x32_bf16(a00, bF[ni][0], acc[4][ni], 0, 0, 0); \
                acc[5][ni] = __builtin_amdgcn_mfma_f32_16x16x32_bf16(a10, bF[ni][0], acc[5][ni], 0, 0, 0); \
                acc[4][ni] = __builtin_amdgcn_mfma_f32_16x16x32_bf16(a01, bF[ni][1], acc[4][ni], 0, 0, 0); \
                acc[5][ni] = __builtin_amdgcn_mfma_f32_16x16x32_bf16(a11, bF[ni][1], acc[5][ni], 0, 0, 0); \
            }                                                                     \
            __builtin_amdgcn_s_setprio(0);                                        \
        }                                                                         \
        {                                                                         \
            short8v a00 = *(const short8v*)(Abuf + frA + 6 * 2048 + ks0);         \
            short8v a01 = *(const short8v*)(Abuf + frA + 6 * 2048 + ks1);         \
            short8v a10 = *(const short8v*)(Abuf + frA + 7 * 2048 + ks0);         \
            short8v a11 = *(const short8v*)(Abuf + frA + 7 * 2048 + ks1);         \
            if (more) { STAGE8G(Asrc, stride_a, 64, kb1, An);                     \
                        STAGE8G(Asrc, stride_a, 192, kb1, An); }                  \
            __builtin_amdgcn_s_setprio(1);                                        \
            _Pragma("unroll")                                                     \
            for (int ni = 0; ni < 4; ++ni) {                                      \
                acc[6][ni] = __builtin_amdgcn_mfma_f32_16x16x32_bf16(a00, bF[ni][0], acc[6][ni], 0, 0, 0); \
                acc[7][ni] = __builtin_amdgcn_mfma_f32_16x16x32_bf16(a10, bF[ni][0], acc[7][ni], 0, 0, 0); \
                acc[6][ni] = __builtin_amdgcn_mfma_f32_16x16x32_bf16(a01, bF[ni][1], acc[6][ni], 0, 0, 0); \
                acc[7][ni] = __builtin_amdgcn_mfma_f32_16x16x32_bf16(a11, bF[ni][1], acc[7][ni], 0, 0, 0); \
            }                                                                     \
            __builtin_amdgcn_s_setprio(0);                                        \
        }                                                                         \
    }

#define GEMM8_PROLOGUE(stride_a, stride_b)                                        \
    {                                                                             \
        unsigned char* A0 = smem;                                                 \
        unsigned char* B0 = smem + 32768;                                         \
        STAGE8G(Bsrc, stride_b, 0,   0, B0); STAGE8G(Bsrc, stride_b, 64,  0, B0); \
        STAGE8G(Bsrc, stride_b, 128, 0, B0); STAGE8G(Bsrc, stride_b, 192, 0, B0); \
        STAGE8G(Asrc, stride_a, 0,   0, A0); STAGE8G(Asrc, stride_a, 128, 0, A0); \
        STAGE8G(Asrc, stride_a, 64,  0, A0); STAGE8G(Asrc, stride_a, 192, 0, A0); \
    }

#define GEMM8_EPI_SCATTER(q)                                                      \
    __syncthreads();                                                              \
    if (wm_ == ((q) >> 1)) {                                                      \
        const int mib = ((q) & 1) * 4;                                            \
        _Pragma("unroll")                                                         \
        for (int m = 0; m < 4; ++m)                                               \
            _Pragma("unroll")                                                     \
            for (int ni = 0; ni < 4; ++ni)                                        \
                _Pragma("unroll")                                                 \
                for (int j = 0; j < 4; ++j) {                                     \
                    const int trow = m * 16 + lg * 4 + j;                         \
                    const int tcol = (wn_ * 64 + ni * 16 + fr) ^ ((trow & 7) << 2); \
                    Tc[trow * 258 + tcol] = acc[mib + m][ni][j];                  \
                }                                                                 \
    }                                                                             \
    __syncthreads();

// ---------------------------------------------------------------------------
// k_down8: H = Xb(bf16) @ downT^T + down_b -> fp32 [TOK][RED]
// ---------------------------------------------------------------------------
__global__ __launch_bounds__(512, 1)
void k_down8(const unsigned short* __restrict__ Xb, const unsigned short* __restrict__ BT,
             const float* __restrict__ bias, float* __restrict__ H)
{
    GEMM8_PREAMBLE(DIM, DIM)
    const int bid = blockIdx.x;                    // 256 blocks
    const int vb = (bid & 7) * 32 + (bid >> 3);
    const int bm = (vb >> 2) * 256, bn = (vb & 3) * 256;
    const unsigned short* Asrc = Xb + (size_t)bm * DIM;
    const unsigned short* Bsrc = BT + (size_t)bn * DIM;

    f32x4 acc[8][4] = {};
    const int NT = DIM / 64;   // 32
    GEMM8_PROLOGUE(DIM, DIM)
    short8v bF[4][2];
    for (int t = 0; t < NT; ++t) {
        unsigned char* Abuf = smem + (t & 1) * 65536;
        unsigned char* Bbuf = Abuf + 32768;
        unsigned char* An   = smem + ((t + 1) & 1) * 65536;
        unsigned char* Bn   = An + 32768;
        const int kb1 = (t + 1) * 64;
        const bool more = (t + 1 < NT);
        GEMM8_TILE(DIM, DIM)
    }
    float* Tc = (float*)smem;
    for (int q = 0; q < 4; ++q) {
        GEMM8_EPI_SCATTER(q)
        const int trow = tid >> 3;
        const int c0 = (tid & 7) * 8;
        const int grow = bm + q * 64 + trow;
        const int colg = bn + c0;
        float* orow = H + (size_t)grow * RED + colg;
        const int sw = (trow & 7) << 2;
#pragma unroll
        for (int ch = 0; ch < 4; ++ch) {
            const int cc = c0 + ch * 64;
            float g[8];
            *(f32x4*)(g)     = *(const f32x4*)&Tc[trow * 258 + (cc ^ sw)];
            *(f32x4*)(g + 4) = *(const f32x4*)&Tc[trow * 258 + ((cc + 4) ^ sw)];
            f32x4 b0 = *(const f32x4*)(bias + colg + ch * 64);
            f32x4 b1 = *(const f32x4*)(bias + colg + ch * 64 + 4);
            f32x4 o0, o1;
#pragma unroll
            for (int k = 0; k < 4; ++k) { o0[k] = g[k] + b0[k]; o1[k] = g[4 + k] + b1[k]; }
            *(f32x4*)(orow + ch * 64)     = o0;
            *(f32x4*)(orow + ch * 64 + 4) = o1;
        }
    }
}

// ---------------------------------------------------------------------------
// k_cross8: stacked-K cross GEMM (K=5120), epilogue ACCb = bf16(poly+gemm*h)
// ---------------------------------------------------------------------------
__global__ __launch_bounds__(512, 1)
void k_cross8(const unsigned short* __restrict__ HP, const unsigned short* __restrict__ CT,
              const unsigned short* __restrict__ POLYb, unsigned short* __restrict__ ACCb)
{
    GEMM8_PREAMBLE(KCR, KCR)
    const int bid = blockIdx.x;                    // 256 blocks
    const int vb = (bid & 7) * 32 + (bid >> 3);
    const int bm = (vb >> 2) * 256, bn = (vb & 3) * 256;
    const unsigned short* Asrc = HP + (size_t)bm * KCR;
    const unsigned short* Bsrc = CT + (size_t)bn * KCR;

    f32x4 acc[8][4] = {};
    const int NT = KCR / 64;   // 80
    GEMM8_PROLOGUE(KCR, KCR)
    short8v bF[4][2];
    for (int t = 0; t < NT; ++t) {
        unsigned char* Abuf = smem + (t & 1) * 65536;
        unsigned char* Bbuf = Abuf + 32768;
        unsigned char* An   = smem + ((t + 1) & 1) * 65536;
        unsigned char* Bn   = An + 32768;
        const int kb1 = (t + 1) * 64;
        const bool more = (t + 1 < NT);
        GEMM8_TILE(KCR, KCR)
    }
    float* Tc = (float*)smem;
    for (int q = 0; q < 4; ++q) {
        GEMM8_EPI_SCATTER(q)
        const int trow = tid >> 3;
        const int c0 = (tid & 7) * 8;
        const int grow = bm + q * 64 + trow;
        const unsigned short* hrow = HP + (size_t)grow * KCR + bn + c0;
        const unsigned short* prow = POLYb + (size_t)grow * RED + bn + c0;
        unsigned short* orow = ACCb + (size_t)grow * RED + bn + c0;
        const int sw = (trow & 7) << 2;
#pragma unroll
        for (int ch = 0; ch < 4; ++ch) {
            const int cc = c0 + ch * 64;
            float g[8];
            *(f32x4*)(g)     = *(const f32x4*)&Tc[trow * 258 + (cc ^ sw)];
            *(f32x4*)(g + 4) = *(const f32x4*)&Tc[trow * 258 + ((cc + 4) ^ sw)];
            u16x8 hh = *(const u16x8*)(hrow + ch * 64);
            u16x8 ppv = *(const u16x8*)(prow + ch * 64);
            u16x8 ov;
#pragma unroll
            for (int k = 0; k < 8; ++k)
                ov[k] = f2bf(bf2f(ppv[k]) + g[k] * bf2f(hh[k]));
            *(u16x8*)(orow + ch * 64) = ov;
        }
    }
}

// ---------------------------------------------------------------------------
// k_up8: OUT = ACCb(bf16) @ upT^T + up_b + X -> fp32 [TOK][DIM]
// ---------------------------------------------------------------------------
__global__ __launch_bounds__(512, 1)
void k_up8(const unsigned short* __restrict__ A, const unsigned short* __restrict__ BT,
           const float* __restrict__ bias, const float* __restrict__ X,
           float* __restrict__ OUT)
{
    GEMM8_PREAMBLE(RED, RED)
    const int bid = blockIdx.x;                    // 512 blocks
    const int vb = (bid & 7) * 64 + (bid >> 3);
    const int bm = (vb >> 3) * 256, bn = (vb & 7) * 256;
    const unsigned short* Asrc = A + (size_t)bm * RED;
    const unsigned short* Bsrc = BT + (size_t)bn * RED;

    f32x4 acc[8][4] = {};
    const int NT = RED / 64;   // 16
    GEMM8_PROLOGUE(RED, RED)
    short8v bF[4][2];
    for (int t = 0; t < NT; ++t) {
        unsigned char* Abuf = smem + (t & 1) * 65536;
        unsigned char* Bbuf = Abuf + 32768;
        unsigned char* An   = smem + ((t + 1) & 1) * 65536;
        unsigned char* Bn   = An + 32768;
        const int kb1 = (t + 1) * 64;
        const bool more = (t + 1 < NT);
        GEMM8_TILE(RED, RED)
    }
    float* Tc = (float*)smem;
    for (int q = 0; q < 4; ++q) {
        GEMM8_EPI_SCATTER(q)
        const int trow = tid >> 3;
        const int c0 = (tid & 7) * 8;
        const int grow = bm + q * 64 + trow;
        const int colg = bn + c0;
        const float* xrow = X + (size_t)grow * DIM + colg;
        float* orow = OUT + (size_t)grow * DIM + colg;
        const int sw = (trow & 7) << 2;
#pragma unroll
        for (int ch = 0; ch < 4; ++ch) {
            const int cc = c0 + ch * 64;
            float g[8];
            *(f32x4*)(g)     = *(const f32x4*)&Tc[trow * 258 + (cc ^ sw)];
            *(f32x4*)(g + 4) = *(const f32x4*)&Tc[trow * 258 + ((cc + 4) ^ sw)];
            f32x4 b0 = *(const f32x4*)(bias + colg + ch * 64);
            f32x4 b1 = *(const f32x4*)(bias + colg + ch * 64 + 4);
            f32x4 x0 = *(const f32x4*)(xrow + ch * 64);
            f32x4 x1 = *(const f32x4*)(xrow + ch * 64 + 4);
            f32x4 o0, o1;
#pragma unroll
            for (int k = 0; k < 4; ++k) {
                o0[k] = g[k] + b0[k] + x0[k];
                o1[k] = g[4 + k] + b1[k] + x1[k];
            }
            *(f32x4*)(orow + ch * 64)     = o0;
            *(f32x4*)(orow + ch * 64 + 4) = o1;
        }
    }
}

// ===========================================================================
// FALLBACK PATH (round-5 verbatim, used when ws_size is too small)
// ===========================================================================
__global__ __launch_bounds__(256)
void k_downS(const float* __restrict__ X, const unsigned short* __restrict__ BT,
             const float* __restrict__ bias, float* __restrict__ H)
{
    __shared__ unsigned short As[128][40];
    __shared__ unsigned short Bs[128][40];
    const int tid = threadIdx.x;
    const int bid = blockIdx.x;
    const int bm = (bid >> 3) * 128, bn = (bid & 7) * 128;
    const int srow = tid >> 1, skq = (tid & 1) << 4;
    const int lane = tid & 63, wave = tid >> 6;
    const int wm = (wave >> 1) << 6, wn = (wave & 1) << 6;
    const int fr = lane & 15, lg = lane >> 4;

    f32x4 acc[4][4] = {};
    const float* ap = X + (size_t)(bm + srow) * DIM + skq;
    const unsigned short* bp = BT + (size_t)(bn + srow) * DIM + skq;

    for (int kb = 0; kb < DIM; kb += 32) {
        float4 a0 = *(const float4*)(ap + kb);
        float4 a1 = *(const float4*)(ap + kb + 4);
        float4 a2 = *(const float4*)(ap + kb + 8);
        float4 a3 = *(const float4*)(ap + kb + 12);
        u16x8 b0 = *(const u16x8*)(bp + kb);
        u16x8 b1 = *(const u16x8*)(bp + kb + 8);
        u16x8 p0, p1;
        p0[0] = f2bf(a0.x); p0[1] = f2bf(a0.y); p0[2] = f2bf(a0.z); p0[3] = f2bf(a0.w);
        p0[4] = f2bf(a1.x); p0[5] = f2bf(a1.y); p0[6] = f2bf(a1.z); p0[7] = f2bf(a1.w);
        p1[0] = f2bf(a2.x); p1[1] = f2bf(a2.y); p1[2] = f2bf(a2.z); p1[3] = f2bf(a2.w);
        p1[4] = f2bf(a3.x); p1[5] = f2bf(a3.y); p1[6] = f2bf(a3.z); p1[7] = f2bf(a3.w);
        __syncthreads();
        *(u16x8*)&As[srow][skq]     = p0;
        *(u16x8*)&As[srow][skq + 8] = p1;
        *(u16x8*)&Bs[srow][skq]     = b0;
        *(u16x8*)&Bs[srow][skq + 8] = b1;
        __syncthreads();
        short8v af[4], bfv[4];
#pragma unroll
        for (int mi = 0; mi < 4; ++mi)
            af[mi] = *(const short8v*)&As[wm + mi * 16 + fr][lg * 8];
#pragma unroll
        for (int ni = 0; ni < 4; ++ni)
            bfv[ni] = *(const short8v*)&Bs[wn + ni * 16 + fr][lg * 8];
#pragma unroll
        for (int mi = 0; mi < 4; ++mi)
#pragma unroll
            for (int ni = 0; ni < 4; ++ni)
                acc[mi][ni] = __builtin_amdgcn_mfma_f32_16x16x32_bf16(
                    af[mi], bfv[ni], acc[mi][ni], 0, 0, 0);
    }
#pragma unroll
    for (int ni = 0; ni < 4; ++ni) {
        const int col = bn + wn + ni * 16 + fr;
        const float bv = bias[col];
#pragma unroll
        for (int mi = 0; mi < 4; ++mi)
#pragma unroll
            for (int j = 0; j < 4; ++j) {
                const int row = bm + wm + mi * 16 + lg * 4 + j;
                H[(size_t)row * RED + col] = acc[mi][ni][j] + bv;
            }
    }
}

__global__ __launch_bounds__(256)
void k_crossS(const float* __restrict__ H, const unsigned short* __restrict__ CT,
              const float* __restrict__ coeffs, unsigned short* __restrict__ ACCb)
{
    __shared__ unsigned short As[128][84];
    __shared__ unsigned short Bs[128][84];
    const int tid = threadIdx.x;
    const int bid = blockIdx.x;
    const int bm = (bid >> 3) * 128;
    const int bn = (bid & 7) * 128;
    const int srow = tid >> 1, sc = (tid & 1) << 4;
    const int lane = tid & 63, wave = tid >> 6;
    const int wm = (wave >> 1) << 6, wn = (wave & 1) << 6;
    const int fr = lane & 15, lg = lane >> 4;

    f32x4 acc[4][4] = {};
    const float* hp = H + (size_t)(bm + srow) * RED + sc;
    const unsigned short* bp = CT + (size_t)(bn + srow) * KCR + sc;

    for (int g = 0; g < 3; ++g) {
        const bool two = (g < 2);
        const unsigned short* bp0 = bp + (2 * g) * RED;
        const unsigned short* bp1 = bp + (2 * g + 1) * RED;
        for (int rb = 0; rb < RED; rb += 32) {
            float4 h0 = *(const float4*)(hp + rb);
            float4 h1 = *(const float4*)(hp + rb + 4);
            float4 h2 = *(const float4*)(hp + rb + 8);
            float4 h3 = *(const float4*)(hp + rb + 12);
            u16x8 b00 = *(const u16x8*)(bp0 + rb);
            u16x8 b01 = *(const u16x8*)(bp0 + rb + 8);
            u16x8 b10 = {}, b11 = {};
            if (two) {
                b10 = *(const u16x8*)(bp1 + rb);
                b11 = *(const u16x8*)(bp1 + rb + 8);
            }
            const float v[16] = {h0.x, h0.y, h0.z, h0.w, h1.x, h1.y, h1.z, h1.w,
                                 h2.x, h2.y, h2.z, h2.w, h3.x, h3.y, h3.z, h3.w};
            u16x8 pa0, pa1, pb0, pb1;
#pragma unroll
            for (int j = 0; j < 16; ++j) {
                const float x = v[j];
                float a, b;
                if (g == 0)      { a = x;                  b = x * x; }
                else if (g == 1) { const float x2 = x * x; a = x2 * x;      b = x2 * x2; }
                else             { const float x2 = x * x; a = x2 * x2 * x; b = 0.f; }
                const unsigned short ua = f2bf(a), ub = f2bf(b);
                if (j < 8) { pa0[j] = ua;     pb0[j] = ub; }
                else       { pa1[j - 8] = ua; pb1[j - 8] = ub; }
            }
            __syncthreads();
            *(u16x8*)&As[srow][sc]     = pa0;
            *(u16x8*)&As[srow][sc + 8] = pa1;
            *(u16x8*)&Bs[srow][sc]     = b00;
            *(u16x8*)&Bs[srow][sc + 8] = b01;
            if (two) {
                *(u16x8*)&As[srow][40 + sc]     = pb0;
                *(u16x8*)&As[srow][40 + sc + 8] = pb1;
                *(u16x8*)&Bs[srow][40 + sc]     = b10;
                *(u16x8*)&Bs[srow][40 + sc + 8] = b11;
            }
            __syncthreads();
            {
                short8v afv[4], bfv[4];
#pragma unroll
                for (int mi = 0; mi < 4; ++mi)
                    afv[mi] = *(const short8v*)&As[wm + mi * 16 + fr][lg * 8];
#pragma unroll
                for (int ni = 0; ni < 4; ++ni)
                    bfv[ni] = *(const short8v*)&Bs[wn + ni * 16 + fr][lg * 8];
#pragma unroll
                for (int mi = 0; mi < 4; ++mi)
#pragma unroll
                    for (int ni = 0; ni < 4; ++ni)
                        acc[mi][ni] = __builtin_amdgcn_mfma_f32_16x16x32_bf16(
                            afv[mi], bfv[ni], acc[mi][ni], 0, 0, 0);
            }
            if (two) {
                short8v afv[4], bfv[4];
#pragma unroll
                for (int mi = 0; mi < 4; ++mi)
                    afv[mi] = *(const short8v*)&As[wm + mi * 16 + fr][40 + lg * 8];
#pragma unroll
                for (int ni = 0; ni < 4; ++ni)
                    bfv[ni] = *(const short8v*)&Bs[wn + ni * 16 + fr][40 + lg * 8];
#pragma unroll
                for (int mi = 0; mi < 4; ++mi)
#pragma unroll
                    for (int ni = 0; ni < 4; ++ni)
                        acc[mi][ni] = __builtin_amdgcn_mfma_f32_16x16x32_bf16(
                            afv[mi], bfv[ni], acc[mi][ni], 0, 0, 0);
            }
        }
    }
#pragma unroll
    for (int ni = 0; ni < 4; ++ni) {
        const int col = bn + wn + ni * 16 + fr;
        float cf[NPOW];
#pragma unroll
        for (int d = 0; d < NPOW; ++d) cf[d] = coeffs[d * RED + col];
#pragma unroll
        for (int mi = 0; mi < 4; ++mi)
#pragma unroll
            for (int j = 0; j < 4; ++j) {
                const int row = bm + wm + mi * 16 + lg * 4 + j;
                const float h = H[(size_t)row * RED + col];
                float poly = 0.f, pw = h;
#pragma unroll
                for (int d = 0; d < NPOW; ++d) { poly += pw * cf[d]; pw *= h; }
                ACCb[(size_t)row * RED + col] = f2bf(poly + acc[mi][ni][j] * h);
            }
    }
}

__global__ __launch_bounds__(256)
void k_upS(const unsigned short* __restrict__ A, const unsigned short* __restrict__ BT,
           const float* __restrict__ bias, const float* __restrict__ X,
           float* __restrict__ OUT)
{
    __shared__ unsigned short As[128][40];
    __shared__ unsigned short Bs[128][40];
    const int tid = threadIdx.x;
    const int bid = blockIdx.x;
    const int bm = (bid >> 4) * 128, bn = (bid & 15) * 128;
    const int srow = tid >> 1, skq = (tid & 1) << 4;
    const int lane = tid & 63, wave = tid >> 6;
    const int wm = (wave >> 1) << 6, wn = (wave & 1) << 6;
    const int fr = lane & 15, lg = lane >> 4;

    f32x4 acc[4][4] = {};
    const unsigned short* ap = A + (size_t)(bm + srow) * RED + skq;
    const unsigned short* bp = BT + (size_t)(bn + srow) * RED + skq;

    for (int kb = 0; kb < RED; kb += 32) {
        u16x8 a0 = *(const u16x8*)(ap + kb);
        u16x8 a1 = *(const u16x8*)(ap + kb + 8);
        u16x8 b0 = *(const u16x8*)(bp + kb);
        u16x8 b1 = *(const u16x8*)(bp + kb + 8);
        __syncthreads();
        *(u16x8*)&As[srow][skq]     = a0;
        *(u16x8*)&As[srow][skq + 8] = a1;
        *(u16x8*)&Bs[srow][skq]     = b0;
        *(u16x8*)&Bs[srow][skq + 8] = b1;
        __syncthreads();
        short8v af[4], bfv[4];
#pragma unroll
        for (int mi = 0; mi < 4; ++mi)
            af[mi] = *(const short8v*)&As[wm + mi * 16 + fr][lg * 8];
#pragma unroll
        for (int ni = 0; ni < 4; ++ni)
            bfv[ni] = *(const short8v*)&Bs[wn + ni * 16 + fr][lg * 8];
#pragma unroll
        for (int mi = 0; mi < 4; ++mi)
#pragma unroll
            for (int ni = 0; ni < 4; ++ni)
                acc[mi][ni] = __builtin_amdgcn_mfma_f32_16x16x32_bf16(
                    af[mi], bfv[ni], acc[mi][ni], 0, 0, 0);
    }
#pragma unroll
    for (int ni = 0; ni < 4; ++ni) {
        const int col = bn + wn + ni * 16 + fr;
        const float bv = bias[col];
#pragma unroll
        for (int mi = 0; mi < 4; ++mi)
#pragma unroll
            for (int j = 0; j < 4; ++j) {
                const int row = bm + wm + mi * 16 + lg * 4 + j;
                OUT[(size_t)row * DIM + col] =
                    acc[mi][ni][j] + bv + X[(size_t)row * DIM + col];
            }
    }
}

extern "C" void kernel_launch(void* const* d_in, const int* in_sizes, int n_in,
                              void* d_out, int out_size, void* d_ws, size_t ws_size,
                              hipStream_t stream) {
    const float* x      = (const float*)d_in[0];
    const float* down_w = (const float*)d_in[1];
    const float* down_b = (const float*)d_in[2];
    const float* coeffs = (const float*)d_in[3];
    const float* cross  = (const float*)d_in[4];
    const float* up_w   = (const float*)d_in[5];
    const float* up_b   = (const float*)d_in[6];
    float* out = (float*)d_out;
    unsigned char* w = (unsigned char*)d_ws;

    const size_t needF = 287309824ull;   // known-passing fast-path footprint

    if (ws_size >= needF) {
        // H @0 (64M, dead after k_pow; ACCb aliases it);
        // Xb @64M (dead after k_down8; HP aliases it, written by k_pow)
        float*          H      = (float*)w;
        unsigned short* ACCb   = (unsigned short*)w;                      // alias (H dead)
        unsigned short* Xb     = (unsigned short*)(w + 67108864ull);
        unsigned short* HP     = (unsigned short*)(w + 67108864ull);      // alias (Xb dead)
        unsigned short* POLYb  = (unsigned short*)(w + 234881024ull);     // 32M
        unsigned short* downT  = (unsigned short*)(w + 268435456ull);     // 4M
        unsigned short* crossT = (unsigned short*)(w + 272629760ull);     // 10M
        unsigned short* upT    = (unsigned short*)(w + 283115520ull);     // 4M

        hipFuncSetAttribute((const void*)k_down8,
                            hipFuncAttributeMaxDynamicSharedMemorySize, 131072);
        hipFuncSetAttribute((const void*)k_cross8,
                            hipFuncAttributeMaxDynamicSharedMemorySize, 131072);
        hipFuncSetAttribute((const void*)k_up8,
                            hipFuncAttributeMaxDynamicSharedMemorySize, 131072);

        k_prep  <<<11264, 256, 0, stream>>>(x, Xb, down_w, downT,
                                            cross, crossT, up_w, upT);
        k_down8 <<<TOK / 256 * (RED / 256), 512, 131072, stream>>>(
            Xb, downT, down_b, H);
        k_pow   <<<2048, 256, 0, stream>>>(H, coeffs, HP, POLYb);
        k_cross8<<<TOK / 256 * (RED / 256), 512, 131072, stream>>>(
            HP, crossT, POLYb, ACCb);
        k_up8   <<<TOK / 256 * (DIM / 256), 512, 131072, stream>>>(
            ACCb, upT, up_b, x, out);
    } else {
        float*          H      = (float*)w;
        unsigned short* ACCb   = (unsigned short*)(w + 67108864ull);
        unsigned short* downT  = (unsigned short*)(w + 100663296ull);
        unsigned short* crossT = (unsigned short*)(w + 104857600ull);
        unsigned short* upT    = (unsigned short*)(w + 115343360ull);

        k_tcvt<<<dim3(RED / 32, DIM / 32, 1), dim3(32, 8), 0, stream>>>(
            down_w, downT, DIM, RED, DIM, 0);
        k_tcvt<<<dim3(RED / 32, RED / 32, 5), dim3(32, 8), 0, stream>>>(
            cross, crossT, RED, RED, KCR, RED);
        k_tcvt<<<dim3(DIM / 32, RED / 32, 1), dim3(32, 8), 0, stream>>>(
            up_w, upT, RED, DIM, RED, 0);

        k_downS <<<TOK / 128 * (RED / 128), 256, 0, stream>>>(x, downT, down_b, H);
        k_crossS<<<TOK / 128 * (RED / 128), 256, 0, stream>>>(H, crossT, coeffs, ACCb);
        k_upS   <<<TOK / 128 * (DIM / 128), 256, 0, stream>>>(ACCb, upT, up_b, x, out);
    }
}